// Round 12
// baseline (270.593 us; speedup 1.0000x reference)
//
#include <hip/hip_runtime.h>
#include <hip/hip_fp16.h>
#include <math.h>

#define NEG_SLOPE 0.2f
#define LOG2E 1.44269504088896f

#if __has_builtin(__builtin_amdgcn_exp2f)
#define EXP2(x) __builtin_amdgcn_exp2f(x)
#else
#define EXP2(x) exp2f(x)
#endif

typedef _Float16 half8 __attribute__((ext_vector_type(8)));
typedef float floatx4 __attribute__((ext_vector_type(4)));

// ---------------- L1: pack W1 (blocks 0..15) + zero deg (blocks 16..) --------------
__global__ __launch_bounds__(256) void prep1(const float* __restrict__ W1,
                                             half8* __restrict__ Bpack,
                                             int* __restrict__ deg, int N) {
  if (blockIdx.x < 16) {
    int tid = blockIdx.x * 256 + threadIdx.x;  // 4096 total
    int l = tid & 63;
    int ksnt = tid >> 6;
    int ks = ksnt & 3;
    int nt = ksnt >> 2;
    int col = nt * 16 + (l & 15);
    int krow = ks * 32 + (l >> 4) * 8;
    half8 v;
#pragma unroll
    for (int j = 0; j < 8; j++) v[j] = (_Float16)W1[(krow + j) * 256 + col];
    Bpack[tid] = v;
  } else {
    int i = (blockIdx.x - 16) * 256 + threadIdx.x;
    if (i < N) deg[i] = 0;
  }
}

// ---------------- L2: gemm1 MFMA -> int8 h1 (per-row scale) + att dots ∥ hist+rank --
__global__ __launch_bounds__(256) void phase2(
    const float* __restrict__ x, const half8* __restrict__ Bpack,
    const float* __restrict__ att_s, const float* __restrict__ att_d,
    unsigned char* __restrict__ h1q, float* __restrict__ hscale,
    float* __restrict__ a1s, float* __restrict__ a1d,
    const int* __restrict__ dst, int* __restrict__ deg, int* __restrict__ rank,
    int N, int E, int gemmBlocks, int histBlocks) {
  if ((int)blockIdx.x >= gemmBlocks) {
    int b = blockIdx.x - gemmBlocks;
    for (int e = b * 256 + threadIdx.x; e < E; e += histBlocks * 256)
      rank[e] = atomicAdd(deg + dst[e], 1);
    return;
  }
  const int wave = threadIdx.x >> 6, lane = threadIdx.x & 63;
  const int quad = lane >> 4, li = lane & 15;
  const int n0 = (blockIdx.x * 4 + wave) * 16;
  if (n0 >= N) return;
  floatx4 acc[16];
#pragma unroll
  for (int t = 0; t < 16; t++) acc[t] = (floatx4){0.f, 0.f, 0.f, 0.f};
  const float* xrow = x + (size_t)(n0 + li) * 128;
#pragma unroll
  for (int ks = 0; ks < 4; ks++) {
    float4 xa = *(const float4*)(xrow + ks * 32 + quad * 8);
    float4 xb = *(const float4*)(xrow + ks * 32 + quad * 8 + 4);
    half8 a;
    a[0] = (_Float16)xa.x; a[1] = (_Float16)xa.y;
    a[2] = (_Float16)xa.z; a[3] = (_Float16)xa.w;
    a[4] = (_Float16)xb.x; a[5] = (_Float16)xb.y;
    a[6] = (_Float16)xb.z; a[7] = (_Float16)xb.w;
#pragma unroll
    for (int nt = 0; nt < 16; nt++) {
      half8 b = Bpack[(nt * 4 + ks) * 64 + lane];
      acc[nt] = __builtin_amdgcn_mfma_f32_16x16x32_f16(a, b, acc[nt], 0, 0, 0);
    }
  }
  // int8 quantize: row (m = quad*4 + r) absmax over 256 ch -> scale
#pragma unroll
  for (int r = 0; r < 4; r++) {
    float m = 0.f;
#pragma unroll
    for (int nt = 0; nt < 16; nt++) m = fmaxf(m, fabsf(acc[nt][r]));
#pragma unroll
    for (int off = 8; off > 0; off >>= 1) m = fmaxf(m, __shfl_xor(m, off, 16));
    m = fmaxf(m, 1e-8f);
    float inv = 127.0f / m;
    int node = n0 + quad * 4 + r;
    if (li == 0) hscale[node] = m * (1.0f / 127.0f);
#pragma unroll
    for (int nt = 0; nt < 16; nt++) {
      h1q[(size_t)node * 256 + nt * 16 + li] =
          (unsigned char)(int)(fmaf(acc[nt][r], inv, 128.5f));
    }
  }
  // fused attention dots (fp32 acc, pre-quantization), pre-scaled by log2e
  float as_f[16], ad_f[16];
#pragma unroll
  for (int nt = 0; nt < 16; nt++) {
    as_f[nt] = att_s[nt * 16 + li];
    ad_f[nt] = att_d[nt * 16 + li];
  }
#pragma unroll
  for (int r = 0; r < 4; r++) {
    int node = n0 + quad * 4 + r;
#pragma unroll
    for (int h = 0; h < 4; h++) {
      float vs = 0.f, vd = 0.f;
#pragma unroll
      for (int ntl = 0; ntl < 4; ntl++) {
        int nt = h * 4 + ntl;
        vs = fmaf(acc[nt][r], as_f[nt], vs);
        vd = fmaf(acc[nt][r], ad_f[nt], vd);
      }
#pragma unroll
      for (int off = 8; off > 0; off >>= 1) {
        vs += __shfl_down(vs, off, 16);
        vd += __shfl_down(vd, off, 16);
      }
      if (li == 0) {
        a1s[node * 4 + h] = vs * LOG2E;
        a1d[node * 4 + h] = vd * LOG2E;
      }
    }
  }
}

// ---------------- CSR scan chain (unpadded rows) ----------------
__global__ void scan_local(const int* __restrict__ deg, int* __restrict__ excl,
                           int* __restrict__ bsum, int N) {
  __shared__ int s[256];
  int i = blockIdx.x * 256 + threadIdx.x;
  int v = (i < N) ? deg[i] + 1 : 0;  // +1 self-loop
  s[threadIdx.x] = v;
  __syncthreads();
  for (int off = 1; off < 256; off <<= 1) {
    int t = (threadIdx.x >= off) ? s[threadIdx.x - off] : 0;
    __syncthreads();
    s[threadIdx.x] += t;
    __syncthreads();
  }
  if (i < N) excl[i] = s[threadIdx.x] - v;
  if (threadIdx.x == 255) bsum[blockIdx.x] = s[255];
}

// scan_add2: re-scan bsum in LDS; write rowptr + self-loop edge + self-loop exw
__global__ void scan_add2(const int* __restrict__ excl, const int* __restrict__ bsum,
                          const float* __restrict__ a1s, const float* __restrict__ a1d,
                          int* __restrict__ rowptr, int* __restrict__ elist,
                          float4* __restrict__ exw, int N, int nb) {
  __shared__ int s[256];
  int v = (threadIdx.x < nb) ? bsum[threadIdx.x] : 0;
  s[threadIdx.x] = v;
  __syncthreads();
  for (int off = 1; off < 256; off <<= 1) {
    int t = (threadIdx.x >= off) ? s[threadIdx.x - off] : 0;
    __syncthreads();
    s[threadIdx.x] += t;
    __syncthreads();
  }
  __syncthreads();
  int base = (blockIdx.x > 0) ? s[blockIdx.x - 1] : 0;  // exclusive block offset
  int i = blockIdx.x * 256 + threadIdx.x;
  if (i < N) {
    int r = excl[i] + base;
    rowptr[i] = r;
    elist[r] = i;  // self-loop first
    float4 as = *(const float4*)(a1s + (size_t)i * 4);
    float4 ad = *(const float4*)(a1d + (size_t)i * 4);
    float l0 = as.x + ad.x, l1 = as.y + ad.y, l2 = as.z + ad.z, l3 = as.w + ad.w;
    exw[r] = make_float4(EXP2(fmaxf(l0, NEG_SLOPE * l0)),
                         EXP2(fmaxf(l1, NEG_SLOPE * l1)),
                         EXP2(fmaxf(l2, NEG_SLOPE * l2)),
                         EXP2(fmaxf(l3, NEG_SLOPE * l3)));
  }
  if (blockIdx.x == 0 && threadIdx.x == 0) rowptr[N] = s[nb - 1];  // total = ET
}

// ---------------- scatter + per-edge softmax numerators (4 heads) ----------------
__global__ void scatter_ex(const int* __restrict__ src, const int* __restrict__ dst,
                           const int* __restrict__ rank, const int* __restrict__ rowptr,
                           const float* __restrict__ a1s, const float* __restrict__ a1d,
                           int* __restrict__ elist, float4* __restrict__ exw, int E) {
  int e = blockIdx.x * 256 + threadIdx.x;
  if (e >= E) return;
  int s = src[e], d = dst[e];
  int pos = rowptr[d] + 1 + rank[e];
  elist[pos] = s;
  float4 as = *(const float4*)(a1s + (size_t)s * 4);
  float4 ad = *(const float4*)(a1d + (size_t)d * 4);
  float l0 = as.x + ad.x, l1 = as.y + ad.y, l2 = as.z + ad.z, l3 = as.w + ad.w;
  exw[pos] = make_float4(EXP2(fmaxf(l0, NEG_SLOPE * l0)),
                         EXP2(fmaxf(l1, NEG_SLOPE * l1)),
                         EXP2(fmaxf(l2, NEG_SLOPE * l2)),
                         EXP2(fmaxf(l3, NEG_SLOPE * l3)));
}

// ---------------- agg1: wave-per-node CSR aggregate over int8 h1 (unroll-8),
// precomputed exw + bias1 + ELU + GEMM2 (W2 in LDS, stride 41) + att2 dots ---------
__global__ __launch_bounds__(256) void agg1_fused(
    const int* __restrict__ rowptr, const int* __restrict__ elist,
    const float* __restrict__ exw, const unsigned char* __restrict__ h1q,
    const float* __restrict__ hscale, const float* __restrict__ b1,
    const float* __restrict__ W2, const float* __restrict__ as2,
    const float* __restrict__ ad2, __half* __restrict__ h2,
    float* __restrict__ a2s, float* __restrict__ a2d, int N) {
  __shared__ float w2s[64 * 41];  // lane-stride 41 -> conflict-free
  const int t = threadIdx.x;
  for (int i = t; i < 2560; i += 256) {
    int ch = i / 10, jj = i - ch * 10;
    w2s[(ch >> 2) * 41 + (ch & 3) * 10 + jj] = W2[i];
  }
  __syncthreads();

  const int wave = t >> 6, lane = t & 63;
  const int n = blockIdx.x * 4 + wave;
  if (n >= N) return;
  const int row = rowptr[n];
  const int deg = rowptr[n + 1] - row;
  const int* el = elist + row;
  const int hidx = lane >> 4;
  const float* ew = exw + (size_t)row * 4 + hidx;  // stride-4 contiguous stream

  float den = 0.f, T = 0.f;
  float acc0 = 0.f, acc1 = 0.f, acc2 = 0.f, acc3 = 0.f;
  int j = 0;
  for (; j + 8 <= deg; j += 8) {
    int ss[8];
    float ev[8], sc[8];
    unsigned int qv[8];
#pragma unroll
    for (int u = 0; u < 8; u++) ss[u] = el[j + u];
#pragma unroll
    for (int u = 0; u < 8; u++) {
      ev[u] = ew[(j + u) * 4];
      sc[u] = hscale[ss[u]];
      qv[u] = *(const unsigned int*)(h1q + (size_t)ss[u] * 256 + lane * 4);
    }
#pragma unroll
    for (int u = 0; u < 8; u++) {
      float e = ev[u];
      den += e;
      float se = e * sc[u];
      T += se;
      acc0 = fmaf((float)(qv[u] & 0xffu), se, acc0);
      acc1 = fmaf((float)((qv[u] >> 8) & 0xffu), se, acc1);
      acc2 = fmaf((float)((qv[u] >> 16) & 0xffu), se, acc2);
      acc3 = fmaf((float)(qv[u] >> 24), se, acc3);
    }
  }
  for (; j + 4 <= deg; j += 4) {
    int ss[4];
    float ev[4], sc[4];
    unsigned int qv[4];
#pragma unroll
    for (int u = 0; u < 4; u++) ss[u] = el[j + u];
#pragma unroll
    for (int u = 0; u < 4; u++) {
      ev[u] = ew[(j + u) * 4];
      sc[u] = hscale[ss[u]];
      qv[u] = *(const unsigned int*)(h1q + (size_t)ss[u] * 256 + lane * 4);
    }
#pragma unroll
    for (int u = 0; u < 4; u++) {
      float e = ev[u];
      den += e;
      float se = e * sc[u];
      T += se;
      acc0 = fmaf((float)(qv[u] & 0xffu), se, acc0);
      acc1 = fmaf((float)((qv[u] >> 8) & 0xffu), se, acc1);
      acc2 = fmaf((float)((qv[u] >> 16) & 0xffu), se, acc2);
      acc3 = fmaf((float)(qv[u] >> 24), se, acc3);
    }
  }
  for (; j < deg; j++) {
    int s0 = el[j];
    float e0 = ew[j * 4];
    float sc0 = hscale[s0];
    unsigned int q0 = *(const unsigned int*)(h1q + (size_t)s0 * 256 + lane * 4);
    den += e0;
    float se = e0 * sc0;
    T += se;
    acc0 = fmaf((float)(q0 & 0xffu), se, acc0);
    acc1 = fmaf((float)((q0 >> 8) & 0xffu), se, acc1);
    acc2 = fmaf((float)((q0 >> 16) & 0xffu), se, acc2);
    acc3 = fmaf((float)(q0 >> 24), se, acc3);
  }

  // undo the +128 offset: sum(se*(q-128)) = sum(se*q) - 128*sum(se)
  float corr = 128.0f * T;
  acc0 -= corr; acc1 -= corr; acc2 -= corr; acc3 -= corr;

  float inv = 1.0f / den;
  float4 bb = *(const float4*)(b1 + lane * 4);
  float c0 = fmaf(acc0, inv, bb.x);
  float c1 = fmaf(acc1, inv, bb.y);
  float c2 = fmaf(acc2, inv, bb.z);
  float c3 = fmaf(acc3, inv, bb.w);
  c0 = c0 > 0.f ? c0 : expm1f(c0);
  c1 = c1 > 0.f ? c1 : expm1f(c1);
  c2 = c2 > 0.f ? c2 : expm1f(c2);
  c3 = c3 > 0.f ? c3 : expm1f(c3);
  const float* w0 = w2s + lane * 41;
  float p[10];
#pragma unroll
  for (int jj = 0; jj < 10; jj++)
    p[jj] = fmaf(c0, w0[jj], fmaf(c1, w0[10 + jj], fmaf(c2, w0[20 + jj], c3 * w0[30 + jj])));
#pragma unroll
  for (int jj = 0; jj < 10; jj++) {
#pragma unroll
    for (int off = 32; off > 0; off >>= 1) p[jj] += __shfl_down(p[jj], off, 64);
  }
  if (lane == 0) {
    float ds = 0.f, dd = 0.f;
#pragma unroll
    for (int jj = 0; jj < 10; jj++) {
      h2[(size_t)n * 16 + jj] = __float2half(p[jj]);
      ds = fmaf(p[jj], as2[jj], ds);
      dd = fmaf(p[jj], ad2[jj], dd);
    }
    a2s[n] = ds * LOG2E;
    a2d[n] = dd * LOG2E;
  }
}

// ---------------- agg2: wave-per-node layer-2 aggregate (R10 proven form) ----------
__global__ __launch_bounds__(256) void agg2_csr(
    const int* __restrict__ rowptr, const int* __restrict__ elist,
    const __half* __restrict__ h2, const float* __restrict__ a2s,
    const float* __restrict__ a2d, const float* __restrict__ b2,
    float* __restrict__ out, int N) {
  int wave = threadIdx.x >> 6, lane = threadIdx.x & 63;
  int n = blockIdx.x * 4 + wave;
  if (n >= N) return;
  int row = rowptr[n];
  int deg = rowptr[n + 1] - row;
  const int* el = elist + row;
  float ad = a2d[n];  // pre-scaled
  int g = lane / 10;  // 0..5 active, lanes 60-63 idle
  int c = lane - g * 10;
  float den = 0.f, acc = 0.f;
  if (g < 6) {
    int jj = g;
    for (; jj + 6 < deg; jj += 12) {
      int sA = el[jj], sB = el[jj + 6];
      float lA = a2s[sA] + ad;
      float lB = a2s[sB] + ad;
      __half hA = h2[(size_t)sA * 16 + c];
      __half hB = h2[(size_t)sB * 16 + c];
      float eA = EXP2(fmaxf(lA, NEG_SLOPE * lA));
      float eB = EXP2(fmaxf(lB, NEG_SLOPE * lB));
      den += eA + eB;
      acc = fmaf(eA, __half2float(hA), fmaf(eB, __half2float(hB), acc));
    }
    for (; jj < deg; jj += 6) {
      int s = el[jj];
      float l = a2s[s] + ad;
      float ev = EXP2(fmaxf(l, NEG_SLOPE * l));
      den += ev;
      acc = fmaf(ev, __half2float(h2[(size_t)s * 16 + c]), acc);
    }
  }
  acc += __shfl_down(acc, 30, 64);
  den += __shfl_down(den, 30, 64);
  acc += __shfl_down(acc, 10, 64) + __shfl_down(acc, 20, 64);
  den += __shfl_down(den, 10, 64) + __shfl_down(den, 20, 64);
  if (lane < 10) out[(size_t)n * 10 + lane] = acc / den + b2[lane];
}

extern "C" void kernel_launch(void* const* d_in, const int* in_sizes, int n_in,
                              void* d_out, int out_size, void* d_ws, size_t ws_size,
                              hipStream_t stream) {
  const float* x = (const float*)d_in[0];
  const int* ei = (const int*)d_in[1];
  const float* W1 = (const float*)d_in[2];
  const float* as1 = (const float*)d_in[3];
  const float* ad1 = (const float*)d_in[4];
  const float* b1 = (const float*)d_in[5];
  const float* W2 = (const float*)d_in[6];
  const float* as2 = (const float*)d_in[7];
  const float* ad2 = (const float*)d_in[8];
  const float* b2 = (const float*)d_in[9];
  float* out = (float*)d_out;

  const int N = in_sizes[0] / 128;   // 50000
  const int E = in_sizes[1] / 2;     // 800000
  const int* srcp = ei;
  const int* dstp = ei + E;

  char* ws = (char*)d_ws;
  size_t off = 0;
  auto alloc = [&](size_t nbytes) {
    char* p = ws + off;
    off += (nbytes + 255) & ~(size_t)255;
    return p;
  };
  unsigned char* h1q = (unsigned char*)alloc((size_t)N * 256);
  float* hscale = (float*)alloc((size_t)N * 4);
  half8* Bpack = (half8*)alloc((size_t)4096 * 16);
  float* a1s = (float*)alloc((size_t)N * 4 * 4);
  float* a1d = (float*)alloc((size_t)N * 4 * 4);
  __half* h2 = (__half*)alloc((size_t)N * 16 * 2);
  float* a2sv = (float*)alloc((size_t)N * 4);
  float* a2dv = (float*)alloc((size_t)N * 4);
  int* deg = (int*)alloc((size_t)N * 4);
  int* excl = (int*)alloc((size_t)N * 4);
  int* bsum = (int*)alloc(256 * 4);
  int* rowptr = (int*)alloc((size_t)(N + 1) * 4);
  int* rank = (int*)alloc((size_t)E * 4);
  int* elist = (int*)alloc((size_t)(E + (size_t)N) * 4);
  float4* exw = (float4*)alloc((size_t)(E + (size_t)N) * 16);

  const int nb = (N + 255) / 256;          // 196
  const int gemmBlocks = (N / 16 + 3) / 4; // 782
  const int histBlocks = 512;

  // L1: pack W1 + zero deg
  prep1<<<16 + nb, 256, 0, stream>>>(W1, Bpack, deg, N);
  // L2: gemm1 (MFMA -> int8 + scales, fused att dots) || hist+rank
  phase2<<<gemmBlocks + histBlocks, 256, 0, stream>>>(
      x, Bpack, as1, ad1, h1q, hscale, a1s, a1d, dstp, deg, rank, N, E,
      gemmBlocks, histBlocks);
  // CSR: scan, rowptr + self-loop edge + self-loop exw, scatter + edge exw
  scan_local<<<nb, 256, 0, stream>>>(deg, excl, bsum, N);
  scan_add2<<<nb, 256, 0, stream>>>(excl, bsum, a1s, a1d, rowptr, elist, exw, N, nb);
  scatter_ex<<<(E + 255) / 256, 256, 0, stream>>>(srcp, dstp, rank, rowptr, a1s, a1d,
                                                  elist, exw, E);
  // layer 1 aggregate (+ fused GEMM2 / att2)
  agg1_fused<<<(N + 3) / 4, 256, 0, stream>>>(rowptr, elist, (const float*)exw, h1q,
                                              hscale, b1, W2, as2, ad2, h2, a2sv,
                                              a2dv, N);
  // layer 2 aggregate
  agg2_csr<<<(N + 3) / 4, 256, 0, stream>>>(rowptr, elist, h2, a2sv, a2dv, b2, out, N);
}